// Round 4
// baseline (513.898 us; speedup 1.0000x reference)
//
#include <hip/hip_runtime.h>

#define B_ 4
#define C_ 128
#define L_ 128
#define N_ 64

__device__ __forceinline__ float fget(const float4& v, int e) {
    switch (e) { case 0: return v.x; case 1: return v.y; case 2: return v.z; default: return v.w; }
}

__device__ __forceinline__ void cfma(float4& ar, float4& ai, float kr, float ki,
                                     const float4& vr, const float4& vi) {
    ar.x += kr * vr.x - ki * vi.x; ai.x += kr * vi.x + ki * vr.x;
    ar.y += kr * vr.y - ki * vi.y; ai.y += kr * vi.y + ki * vr.y;
    ar.z += kr * vr.z - ki * vi.z; ai.z += kr * vi.z + ki * vr.z;
    ar.w += kr * vr.w - ki * vi.w; ai.w += kr * vi.w + ki * vr.w;
}

// ---------------- Kernel A: SSM kernels k0,k1 ----------------
// kbuf floats: [k0_re 16384][k0_im 16384][k1_re 16384][k1_im 16384]
__global__ __launch_bounds__(256) void compute_k_kernel(
    const float* __restrict__ logA, const float* __restrict__ Aim,
    const float* __restrict__ Bre, const float* __restrict__ Bim,
    const float* __restrict__ Cre, const float* __restrict__ Cim,
    const float* __restrict__ logdt, float* __restrict__ kbuf)
{
    int idx = blockIdx.x * 256 + threadIdx.x;   // axis*16384 + c*128 + t
    int axis = idx >> 14;
    int c = (idx >> 7) & 127;
    int t = idx & 127;
    float dt = expf(logdt[axis * C_ + c]);
    float tf = (float)t;
    const float* lA = logA + (axis * C_ + c) * N_;
    const float* br = Bre + (axis * C_ + c) * N_;
    const float* bi = Bim + (axis * C_ + c) * N_;
    const float* cr = Cre + (axis * C_ + c) * N_;
    const float* ci = Cim + (axis * C_ + c) * N_;
    const float* ai = Aim + axis * N_;
    float kr = 0.f, ki = 0.f;
    for (int n = 0; n < N_; ++n) {
        float zre = -expf(lA[n]) * dt;
        float zim = ai[n] * dt;
        float mag = expf(zre * tf);
        float s, co;
        sincosf(zim * tf, &s, &co);
        float wr = mag * co, wi = mag * s;
        float cbr = cr[n] * br[n] - ci[n] * bi[n];
        float cbi = cr[n] * bi[n] + ci[n] * br[n];
        kr += cbr * wr - cbi * wi;
        ki += cbr * wi + cbi * wr;
    }
    kbuf[axis * 32768 + c * L_ + t] = kr;
    kbuf[axis * 32768 + 16384 + c * L_ + t] = ki;
}

// ---------------- conv_x: z1(x,y) = sum_{a<=x} k0[x-a]*u(a,y) ----------------
// Block: (b, c, y-half). LDS [a=128][y64] swizzled. Wave-banded triangular x loop.
// Natural coalesced output: z1_re -> ws, z1_im -> d_out.
__global__ __launch_bounds__(512) void conv_x_kernel(
    const float* __restrict__ u_re, const float* __restrict__ u_im,
    const float* __restrict__ kbuf, float* __restrict__ z_re, float* __restrict__ z_im)
{
    __shared__ float sre[128 * 64];
    __shared__ float sim[128 * 64];
    __shared__ float ktr[136], kti[136];
    int blk = blockIdx.x;
    int half = blk & 1;
    int c = (blk >> 1) & 127;
    int b = blk >> 8;
    int tid = threadIdx.x;
    if (tid < 136) {
        int t = tid - 7;
        bool v = (t >= 0) && (t < 128);
        ktr[tid] = v ? kbuf[c * 128 + t] : 0.f;
        kti[tid] = v ? kbuf[16384 + c * 128 + t] : 0.f;
    }
    size_t base = (size_t)(b * 128 + c) * 16384;
#pragma unroll
    for (int it = 0; it < 4; ++it) {
        int i4 = it * 512 + tid;
        int r = i4 >> 4, c4 = i4 & 15;
        float4 vr = *(const float4*)(u_re + base + r * 128 + half * 64 + 4 * c4);
        float4 vi = *(const float4*)(u_im + base + r * 128 + half * 64 + 4 * c4);
        int p = r * 64 + 4 * (c4 ^ (r & 15));
        *(float4*)&sre[p] = vr;
        *(float4*)&sim[p] = vi;
    }
    __syncthreads();
    int w = tid >> 6;
    int wb = half ? (7 - w) : w;            // parity flip: co-resident blocks complement
    int lane = tid & 63;
    int rq = 4 * wb + ((lane >> 4) & 3);    // output x-block 0..31
    int cq = lane & 15;                     // y float4-col
    int r0 = 4 * rq;
    int abound = 16 * wb + 15;              // wave-uniform triangular bound
    float4 accr[4], acci[4];
#pragma unroll
    for (int k = 0; k < 4; ++k) {
        accr[k] = make_float4(0.f, 0.f, 0.f, 0.f);
        acci[k] = make_float4(0.f, 0.f, 0.f, 0.f);
    }
    for (int a = 0; a <= abound; ++a) {
        int p = a * 64 + 4 * (cq ^ (a & 15));
        float4 vr = *(const float4*)&sre[p];
        float4 vi = *(const float4*)&sim[p];
        int jb = r0 - a + 7;
#pragma unroll
        for (int k = 0; k < 4; ++k) {
            int j = jb + k; j = j < 0 ? 0 : j;
            cfma(accr[k], acci[k], ktr[j], kti[j], vr, vi);
        }
    }
#pragma unroll
    for (int k = 0; k < 4; ++k) {
        *(float4*)(z_re + base + (size_t)(r0 + k) * 128 + half * 64 + 4 * cq) = accr[k];
        *(float4*)(z_im + base + (size_t)(r0 + k) * 128 + half * 64 + 4 * cq) = acci[k];
    }
}

// ---------------- conv_y: z2(x,y) = sum_{j<=y} k1[y-j]*z1(x,j) ----------------
// Block: (b, c, x-half). Stage z1 rows x (contiguous) transposed into LDS [j=128][x64].
// Banded triangular y loop; un-transpose output through LDS; in-place per-block:
// reads z1_re(ws)+z1_im(d_out) of own range, writes z2_re->d_out, z2_im->ws same range.
__global__ __launch_bounds__(512) void conv_y_kernel(
    float* __restrict__ z_re /* ws: z1_re in, z2_im out */,
    float* __restrict__ z_im /* d_out: z1_im in, z2_re out */,
    const float* __restrict__ kbuf)
{
    __shared__ float sre[128 * 64];
    __shared__ float sim[128 * 64];
    __shared__ float ktr[136], kti[136];
    int blk = blockIdx.x;
    int half = blk & 1;
    int c = (blk >> 1) & 127;
    int b = blk >> 8;
    int tid = threadIdx.x;
    if (tid < 136) {
        int t = tid - 7;
        bool v = (t >= 0) && (t < 128);
        ktr[tid] = v ? kbuf[32768 + c * 128 + t] : 0.f;
        kti[tid] = v ? kbuf[49152 + c * 128 + t] : 0.f;
    }
    size_t base = (size_t)(b * 128 + c) * 16384;
    // stage + transpose: global rows x (64), 128 y each -> LDS [y][x] swizzled
#pragma unroll
    for (int it = 0; it < 4; ++it) {
        int i4 = it * 512 + tid;
        int xl = i4 >> 5, q = i4 & 31;
        float4 vr = *(const float4*)(z_re + base + (size_t)(half * 64 + xl) * 128 + 4 * q);
        float4 vi = *(const float4*)(z_im + base + (size_t)(half * 64 + xl) * 128 + 4 * q);
        int c4 = xl >> 2, e0 = xl & 3;
#pragma unroll
        for (int e = 0; e < 4; ++e) {
            int y = 4 * q + e;
            int p = y * 64 + 4 * (c4 ^ (y & 15)) + e0;
            sre[p] = fget(vr, e);
            sim[p] = fget(vi, e);
        }
    }
    __syncthreads();
    int w = tid >> 6;
    int wb = half ? (7 - w) : w;
    int lane = tid & 63;
    int rq = 4 * wb + ((lane >> 4) & 3);    // output y-block 0..31
    int cq = lane & 15;                     // x float4-col
    int r0 = 4 * rq;
    int abound = 16 * wb + 15;
    float4 accr[4], acci[4];
#pragma unroll
    for (int k = 0; k < 4; ++k) {
        accr[k] = make_float4(0.f, 0.f, 0.f, 0.f);
        acci[k] = make_float4(0.f, 0.f, 0.f, 0.f);
    }
    for (int a = 0; a <= abound; ++a) {      // a = j
        int p = a * 64 + 4 * (cq ^ (a & 15));
        float4 vr = *(const float4*)&sre[p];
        float4 vi = *(const float4*)&sim[p];
        int jb = r0 - a + 7;
#pragma unroll
        for (int k = 0; k < 4; ++k) {
            int j = jb + k; j = j < 0 ? 0 : j;
            cfma(accr[k], acci[k], ktr[j], kti[j], vr, vi);
        }
    }
    __syncthreads();
    // transpose acc through LDS: T[cc=x 64][o=y 128], swizzle o4' = o4 ^ (cc>>2)
#pragma unroll
    for (int e = 0; e < 4; ++e) {
        int cc = 4 * cq + e;
        int p = cc * 128 + 4 * (rq ^ (cc >> 2));
        *(float4*)&sre[p] = make_float4(fget(accr[0], e), fget(accr[1], e), fget(accr[2], e), fget(accr[3], e));
        *(float4*)&sim[p] = make_float4(fget(acci[0], e), fget(acci[1], e), fget(acci[2], e), fget(acci[3], e));
    }
    __syncthreads();
    int cc = tid >> 3, fq = tid & 7;
#pragma unroll
    for (int mm = 0; mm < 4; ++mm) {
        int o4 = fq + 8 * mm;
        int p = cc * 128 + 4 * (o4 ^ (cc >> 2));
        float4 vre = *(float4*)&sre[p];   // z2_re
        float4 vim = *(float4*)&sim[p];   // z2_im
        *(float4*)(z_im + base + (size_t)(half * 64 + cc) * 128 + 4 * o4) = vre;  // -> d_out
        *(float4*)(z_re + base + (size_t)(half * 64 + cc) * 128 + 4 * o4) = vim;  // -> ws
    }
}

// ---------------- mix: out[b,d,s] = sum_c Wre[d,c]*z2re[b,c,s] - Wim[d,c]*z2im[b,c,s] ----------------
// Block: (b, x-row of 128 s). In-place on d_out (reads (c,x-row), writes (d,x-row) after c-loop).
__global__ __launch_bounds__(256) void mix_kernel(
    float* __restrict__ zre /* d_out */, const float* __restrict__ zim /* ws */,
    const float* __restrict__ Wre, const float* __restrict__ Wim)
{
    __shared__ float zr_s[16][128];
    __shared__ float zi_s[16][128];
    __shared__ float wr_s[16][132];
    __shared__ float wi_s[16][132];
    int bid = blockIdx.x;
    int b = bid >> 7, x = bid & 127;
    int tid = threadIdx.x;
    int sq = tid & 15, dq = tid >> 4;
    float acc[8][8];
#pragma unroll
    for (int di = 0; di < 8; ++di)
#pragma unroll
        for (int si = 0; si < 8; ++si) acc[di][si] = 0.f;

    for (int c0 = 0; c0 < 128; c0 += 16) {
        __syncthreads();
#pragma unroll
        for (int it = 0; it < 2; ++it) {
            int i4 = it * 256 + tid;
            int cc = i4 >> 5, y4 = i4 & 31;
            size_t g = (size_t)(b * 128 + c0 + cc) * 16384 + x * 128 + 4 * y4;
            *(float4*)&zr_s[cc][4 * y4] = *(const float4*)(zre + g);
            *(float4*)&zi_s[cc][4 * y4] = *(const float4*)(zim + g);
        }
#pragma unroll
        for (int it = 0; it < 8; ++it) {
            int i = it * 256 + tid;
            int d = i >> 4, cc = i & 15;
            wr_s[cc][d] = Wre[d * 128 + c0 + cc];
            wi_s[cc][d] = Wim[d * 128 + c0 + cc];
        }
        __syncthreads();
#pragma unroll
        for (int cc = 0; cc < 16; ++cc) {
            float4 w0 = *(float4*)&wr_s[cc][4 * dq];
            float4 w1 = *(float4*)&wr_s[cc][64 + 4 * dq];
            float4 v0 = *(float4*)&wi_s[cc][4 * dq];
            float4 v1 = *(float4*)&wi_s[cc][64 + 4 * dq];
            float4 r0v = *(float4*)&zr_s[cc][4 * sq];
            float4 r1v = *(float4*)&zr_s[cc][64 + 4 * sq];
            float4 i0v = *(float4*)&zi_s[cc][4 * sq];
            float4 i1v = *(float4*)&zi_s[cc][64 + 4 * sq];
            float wr[8] = {w0.x, w0.y, w0.z, w0.w, w1.x, w1.y, w1.z, w1.w};
            float wi[8] = {v0.x, v0.y, v0.z, v0.w, v1.x, v1.y, v1.z, v1.w};
            float zr[8] = {r0v.x, r0v.y, r0v.z, r0v.w, r1v.x, r1v.y, r1v.z, r1v.w};
            float zi[8] = {i0v.x, i0v.y, i0v.z, i0v.w, i1v.x, i1v.y, i1v.z, i1v.w};
#pragma unroll
            for (int di = 0; di < 8; ++di)
#pragma unroll
                for (int si = 0; si < 8; ++si)
                    acc[di][si] += wr[di] * zr[si] - wi[di] * zi[si];
        }
    }
#pragma unroll
    for (int di = 0; di < 8; ++di) {
        int d = (di < 4) ? (4 * dq + di) : (64 + 4 * dq + di - 4);
        float* o = zre + (size_t)(b * 128 + d) * 16384 + x * 128;
        *(float4*)&o[4 * sq] = make_float4(acc[di][0], acc[di][1], acc[di][2], acc[di][3]);
        *(float4*)&o[64 + 4 * sq] = make_float4(acc[di][4], acc[di][5], acc[di][6], acc[di][7]);
    }
}

extern "C" void kernel_launch(void* const* d_in, const int* in_sizes, int n_in,
                              void* d_out, int out_size, void* d_ws, size_t ws_size,
                              hipStream_t stream) {
    const float* u_re  = (const float*)d_in[0];
    const float* u_im  = (const float*)d_in[1];
    const float* logA  = (const float*)d_in[2];
    const float* Aim   = (const float*)d_in[3];
    const float* Bre   = (const float*)d_in[4];
    const float* Bim   = (const float*)d_in[5];
    const float* Cre   = (const float*)d_in[6];
    const float* Cim   = (const float*)d_in[7];
    const float* logdt = (const float*)d_in[8];
    const float* Wre   = (const float*)d_in[9];
    const float* Wim   = (const float*)d_in[10];
    float* kbuf = (float*)d_ws;                 // 256 KB
    float* wsA  = (float*)d_ws + 65536;         // 33.5 MB: z1_re, then z2_im
    float* outp = (float*)d_out;                // z1_im, then z2_re, then final

    hipLaunchKernelGGL(compute_k_kernel, dim3(128), dim3(256), 0, stream,
                       logA, Aim, Bre, Bim, Cre, Cim, logdt, kbuf);
    hipLaunchKernelGGL(conv_x_kernel, dim3(B_ * C_ * 2), dim3(512), 0, stream,
                       u_re, u_im, kbuf, wsA, outp);
    hipLaunchKernelGGL(conv_y_kernel, dim3(B_ * C_ * 2), dim3(512), 0, stream,
                       wsA, outp, kbuf);
    hipLaunchKernelGGL(mix_kernel, dim3(B_ * 128), dim3(256), 0, stream,
                       outp, wsA, Wre, Wim);
}